// Round 1
// baseline (44.485 us; speedup 1.0000x reference)
//
#include <hip/hip_runtime.h>

// Inverse DWT step (8-tap, circular, ortho-normalized) as direct polyphase conv.
// out[r][2k]   = (1/128) * sum_{s=0..3} wav[7-2s]*det[r][k-s] + scl[7-2s]*app[r][k-s]
// out[r][2k+1] = (1/128) * sum_{s=0..3} wav[6-2s]*det[r][k-s] + scl[6-2s]*app[r][k-s]
// (k-s taken mod m, circular)

__global__ __launch_bounds__(256) void idwt_kernel(
    const float* __restrict__ det,
    const float* __restrict__ app,
    const float* __restrict__ wav,
    const float* __restrict__ scl,
    float* __restrict__ out,
    int m, float scale)
{
    const int r  = blockIdx.y;
    const int kb = blockIdx.x * blockDim.x + threadIdx.x;
    const int k0 = kb * 4;
    if (k0 >= m) return;

    // Filter taps, pre-scaled by 1/sqrt(N). Uniform (scalar-cached) loads.
    float we[4], wo[4], se[4], so[4];
#pragma unroll
    for (int t = 0; t < 4; ++t) {
        we[t] = wav[7 - 2 * t] * scale;
        wo[t] = wav[6 - 2 * t] * scale;
        se[t] = scl[7 - 2 * t] * scale;
        so[t] = scl[6 - 2 * t] * scale;
    }

    const size_t row_in = (size_t)r * (size_t)m;
    const int km4 = (k0 == 0) ? (m - 4) : (k0 - 4);   // circular wrap

    const float4 d1 = *(const float4*)(det + row_in + k0);
    const float4 a1 = *(const float4*)(app + row_in + k0);
    const float4 d0 = *(const float4*)(det + row_in + km4);
    const float4 a0 = *(const float4*)(app + row_in + km4);

    // Window: dw[i] = det[r][k0-4+i] (mod m), i=0..7; same for aw.
    float dw[8] = {d0.x, d0.y, d0.z, d0.w, d1.x, d1.y, d1.z, d1.w};
    float aw[8] = {a0.x, a0.y, a0.z, a0.w, a1.x, a1.y, a1.z, a1.w};

    float res[8];
#pragma unroll
    for (int j = 0; j < 4; ++j) {          // k = k0 + j
        float e = 0.f, o = 0.f;
#pragma unroll
        for (int t = 0; t < 4; ++t) {      // d[k-t] = dw[j+4-t]
            const float d = dw[j + 4 - t];
            const float a = aw[j + 4 - t];
            e = fmaf(we[t], d, e);
            e = fmaf(se[t], a, e);
            o = fmaf(wo[t], d, o);
            o = fmaf(so[t], a, o);
        }
        res[2 * j]     = e;
        res[2 * j + 1] = o;
    }

    float* orow = out + (size_t)r * (size_t)(2 * m) + (size_t)(2 * k0);
    *(float4*)(orow)     = make_float4(res[0], res[1], res[2], res[3]);
    *(float4*)(orow + 4) = make_float4(res[4], res[5], res[6], res[7]);
}

extern "C" void kernel_launch(void* const* d_in, const int* in_sizes, int n_in,
                              void* d_out, int out_size, void* d_ws, size_t ws_size,
                              hipStream_t stream) {
    const float* det = (const float*)d_in[0];
    const float* app = (const float*)d_in[1];
    const float* wav = (const float*)d_in[2];
    const float* scl = (const float*)d_in[3];
    float* out = (float*)d_out;

    const int m      = 8192;                  // reference: details is (2048, 8192)
    const int n_rows = in_sizes[0] / m;       // 2048
    const float scale = 1.0f / 128.0f;        // 1/sqrt(2m) = 1/sqrt(16384)

    dim3 block(256);
    dim3 grid((m / 4 + 255) / 256, n_rows);   // (8, 2048)
    idwt_kernel<<<grid, block, 0, stream>>>(det, app, wav, scl, out, m, scale);
}